// Round 1
// baseline (22982.513 us; speedup 1.0000x reference)
//
#include <hip/hip_runtime.h>
#include <math.h>

#define NVOX 8192
#define CCH 768
#define NH 12
#define DH 64
#define NBLK 12
#define NG 32
#define OUT_CH 448
#define CAPMAX 64

// ---------------------------------------------------------------------------
// prep: cap = max(vslot)+1 for both window configs
// ---------------------------------------------------------------------------
__global__ __launch_bounds__(256) void cap_kernel(const int* __restrict__ a,
                                                  const int* __restrict__ b,
                                                  int n, int* __restrict__ caps) {
  __shared__ int s0[256], s1[256];
  int m0 = 0, m1 = 0;
  for (int i = threadIdx.x; i < n; i += 256) {
    m0 = max(m0, a[i]);
    m1 = max(m1, b[i]);
  }
  s0[threadIdx.x] = m0;
  s1[threadIdx.x] = m1;
  __syncthreads();
  for (int st = 128; st > 0; st >>= 1) {
    if (threadIdx.x < st) {
      s0[threadIdx.x] = max(s0[threadIdx.x], s0[threadIdx.x + st]);
      s1[threadIdx.x] = max(s1[threadIdx.x], s1[threadIdx.x + st]);
    }
    __syncthreads();
  }
  if (threadIdx.x == 0) {
    caps[0] = s0[0] + 1;
    caps[1] = s1[0] + 1;
  }
}

// ---------------------------------------------------------------------------
// embed: h = feats @ in_w + in_b + pos_embed(coords)
// ---------------------------------------------------------------------------
__global__ __launch_bounds__(256) void embed_kernel(const float* __restrict__ feats,
                                                    const int* __restrict__ coords,
                                                    const float* __restrict__ in_w,
                                                    const float* __restrict__ in_b,
                                                    float* __restrict__ h) {
  int id = blockIdx.x * 256 + threadIdx.x;
  if (id >= NVOX * CCH) return;
  int n = id / CCH, c = id - n * CCH;
  float acc = in_b[c];
#pragma unroll
  for (int k = 0; k < 8; ++k) acc += feats[n * 8 + k] * in_w[k * CCH + c];
  int axis = c / 256;
  int r = c - axis * 256;
  int f = r & 127;
  // freqs[f] = 10000^(-f/128)
  float freq = __expf(-(float)f * (9.210340371976184f / 128.0f));  // ln(10000)
  float phase = (float)coords[n * 3 + axis] * freq;
  acc += (r < 128) ? __sinf(phase) : __cosf(phase);
  h[id] = acc;
}

// ---------------------------------------------------------------------------
// layernorm (no affine), eps parameter
// ---------------------------------------------------------------------------
__global__ __launch_bounds__(256) void ln_kernel(const float* __restrict__ x,
                                                 float* __restrict__ y, float eps) {
  int row = blockIdx.x;
  const float* xr = x + (size_t)row * CCH;
  float v[3];
  float s = 0.f, s2 = 0.f;
#pragma unroll
  for (int j = 0; j < 3; ++j) {
    v[j] = xr[threadIdx.x + j * 256];
    s += v[j];
    s2 += v[j] * v[j];
  }
#pragma unroll
  for (int off = 32; off >= 1; off >>= 1) {
    s += __shfl_xor(s, off, 64);
    s2 += __shfl_xor(s2, off, 64);
  }
  __shared__ float ss[4], ss2[4];
  int wave = threadIdx.x >> 6, lane = threadIdx.x & 63;
  if (lane == 0) { ss[wave] = s; ss2[wave] = s2; }
  __syncthreads();
  s = ss[0] + ss[1] + ss[2] + ss[3];
  s2 = ss2[0] + ss2[1] + ss2[2] + ss2[3];
  float mu = s * (1.0f / CCH);
  float var = s2 * (1.0f / CCH) - mu * mu;
  float rr = rsqrtf(var + eps);
  float* yr = y + (size_t)row * CCH;
#pragma unroll
  for (int j = 0; j < 3; ++j) yr[threadIdx.x + j * 256] = (v[j] - mu) * rr;
}

// ---------------------------------------------------------------------------
// tiled fp32 GEMM: out[M,Nn] = act(A[M,K] @ W[K,Nn] + bias) (+ out if RES)
// 64x64 tile, BK=16, 256 threads, 4x4 microtile. All dims divisible.
// ---------------------------------------------------------------------------
__device__ __forceinline__ float gelu_exact(float x) {
  return 0.5f * x * (1.0f + erff(x * 0.70710678118654752f));
}

template <int ACT, int RES>
__global__ __launch_bounds__(256) void gemm_kernel(const float* __restrict__ A,
                                                   const float* __restrict__ W,
                                                   const float* __restrict__ bias,
                                                   float* __restrict__ out,
                                                   int M, int Nn, int K) {
  __shared__ float As[16][68];  // [k][m], padded row (68 floats keeps 16B align)
  __shared__ float Bs[16][64];  // [k][n]
  const int tid = threadIdx.x;
  const int tx = tid & 15, ty = tid >> 4;
  const int row0 = blockIdx.y * 64, col0 = blockIdx.x * 64;
  const int lar = tid >> 2;          // 0..63  (A row within tile)
  const int lak = (tid & 3) << 2;    // 0,4,8,12 (A k within tile)
  const int lbk = tid >> 4;          // 0..15  (B k within tile)
  const int lbn = (tid & 15) << 2;   // 0..60  (B n within tile)
  float acc[4][4] = {{0.f}};
  const float* Aptr = A + (size_t)(row0 + lar) * K + lak;
  for (int k0 = 0; k0 < K; k0 += 16) {
    float4 a4 = *(const float4*)(Aptr + k0);
    float4 b4 = *(const float4*)(W + (size_t)(k0 + lbk) * Nn + col0 + lbn);
    As[lak + 0][lar] = a4.x;
    As[lak + 1][lar] = a4.y;
    As[lak + 2][lar] = a4.z;
    As[lak + 3][lar] = a4.w;
    *(float4*)&Bs[lbk][lbn] = b4;
    __syncthreads();
#pragma unroll
    for (int kk = 0; kk < 16; ++kk) {
      float4 av = *(const float4*)&As[kk][ty << 2];
      float4 bv = *(const float4*)&Bs[kk][tx << 2];
      float a[4] = {av.x, av.y, av.z, av.w};
      float b[4] = {bv.x, bv.y, bv.z, bv.w};
#pragma unroll
      for (int i = 0; i < 4; ++i)
#pragma unroll
        for (int j = 0; j < 4; ++j) acc[i][j] = fmaf(a[i], b[j], acc[i][j]);
    }
    __syncthreads();
  }
#pragma unroll
  for (int i = 0; i < 4; ++i) {
    int r = row0 + (ty << 2) + i;
    size_t o = (size_t)r * Nn + col0 + (tx << 2);
    float vj[4];
#pragma unroll
    for (int j = 0; j < 4; ++j) {
      float v = acc[i][j] + bias[col0 + (tx << 2) + j];
      if (ACT == 1) v = gelu_exact(v);
      vj[j] = v;
    }
    float4 res;
    if (RES) {
      float4 old = *(const float4*)(out + o);
      res = make_float4(old.x + vj[0], old.y + vj[1], old.z + vj[2], old.w + vj[3]);
    } else {
      res = make_float4(vj[0], vj[1], vj[2], vj[3]);
    }
    *(float4*)(out + o) = res;
  }
}

// ---------------------------------------------------------------------------
// windowed attention: one (window, head) per block iteration; wave per query.
// qkv layout [N, 2304]: q|k|v each [NH,DH]. Scatters output per voxel.
// ---------------------------------------------------------------------------
__global__ __launch_bounds__(256) void attn_kernel(const float* __restrict__ qkv,
                                                   const int* __restrict__ idx,
                                                   const int* __restrict__ capPtr,
                                                   int total,
                                                   float* __restrict__ attn_out) {
  __shared__ float k_lds[CAPMAX][DH];
  __shared__ float v_lds[CAPMAX][DH];
  __shared__ int vox_lds[CAPMAX];
  const int cap = *capPtr;
  if (cap > CAPMAX) return;  // data guarantees cap ~<= 40
  const int nw = total / cap;
  const int tasks = nw * NH;
  const int tid = threadIdx.x;
  const int wave = tid >> 6, lane = tid & 63;
  for (int task = blockIdx.x; task < tasks; task += gridDim.x) {
    const int w = task / NH, hh = task - w * NH;
    if (tid < cap) vox_lds[tid] = idx[w * cap + tid];
    __syncthreads();
    for (int e = tid; e < cap * DH; e += 256) {
      int s = e >> 6, d = e & 63;
      int vox = vox_lds[s];
      float kv = 0.f, vv = 0.f;
      if (vox < NVOX) {
        const float* base = qkv + (size_t)vox * (3 * CCH) + hh * DH + d;
        kv = base[CCH];
        vv = base[2 * CCH];
      }
      k_lds[s][d] = kv;
      v_lds[s][d] = vv;
    }
    __syncthreads();
    for (int s = wave; s < cap; s += 4) {
      int vox = vox_lds[s];
      if (vox < NVOX) {
        float qv = qkv[(size_t)vox * (3 * CCH) + hh * DH + lane] * 0.125f;
        float myscore = -1e30f;
        for (int j = 0; j < cap; ++j) {
          float p = qv * k_lds[j][lane];
#pragma unroll
          for (int off = 32; off >= 1; off >>= 1) p += __shfl_xor(p, off, 64);
          if (lane == j && vox_lds[j] < NVOX) myscore = p;
        }
        float m = myscore;
#pragma unroll
        for (int off = 32; off >= 1; off >>= 1) m = fmaxf(m, __shfl_xor(m, off, 64));
        float e = (myscore > -1e29f) ? __expf(myscore - m) : 0.f;
        float den = e;
#pragma unroll
        for (int off = 32; off >= 1; off >>= 1) den += __shfl_xor(den, off, 64);
        float p = e / den;
        float o = 0.f;
        for (int j = 0; j < cap; ++j) {
          float pj = __shfl(p, j, 64);
          o = fmaf(pj, v_lds[j][lane], o);
        }
        attn_out[(size_t)vox * CCH + hh * DH + lane] = o;
      }
    }
    __syncthreads();
  }
}

// ---------------------------------------------------------------------------
// gaussian decode, in-place on d_out rows of 448 (LDS-staged so safe)
// ---------------------------------------------------------------------------
__global__ __launch_bounds__(256) void decode_kernel(float* __restrict__ out,
                                                     const int* __restrict__ coords,
                                                     const float* __restrict__ perturb) {
  __shared__ float row[OUT_CH];
  const int n = blockIdx.x;
  float* o = out + (size_t)n * OUT_CH;
  for (int e = threadIdx.x; e < OUT_CH; e += 256) row[e] = o[e];
  __syncthreads();
  for (int e = threadIdx.x; e < OUT_CH; e += 256) {
    int g = e / 14, j = e - g * 14;
    float v;
    if (j < 3) {
      float xyz = ((float)coords[n * 3 + j] + 0.5f) * (1.0f / 64.0f);
      v = xyz + tanhf(row[g * 3 + j] + perturb[g * 3 + j]) * (0.75f / 64.0f);
    } else if (j < 6) {
      v = row[96 + g * 3 + (j - 3)];
    } else if (j < 9) {
      v = row[192 + g * 3 + (j - 6)];
    } else if (j < 13) {
      v = row[288 + g * 4 + (j - 9)] * 0.1f;
    } else {
      v = row[416 + g];
    }
    o[e] = v;
  }
}

// ---------------------------------------------------------------------------
extern "C" void kernel_launch(void* const* d_in, const int* in_sizes, int n_in,
                              void* d_out, int out_size, void* d_ws, size_t ws_size,
                              hipStream_t stream) {
  const float* feats = (const float*)d_in[0];
  const int* coords = (const int*)d_in[1];
  const float* in_w = (const float*)d_in[2];
  const float* in_b = (const float*)d_in[3];
  const float* qkv_w = (const float*)d_in[4];
  const float* qkv_b = (const float*)d_in[5];
  const float* proj_w = (const float*)d_in[6];
  const float* proj_b = (const float*)d_in[7];
  const float* mlp_w1 = (const float*)d_in[8];
  const float* mlp_b1 = (const float*)d_in[9];
  const float* mlp_w2 = (const float*)d_in[10];
  const float* mlp_b2 = (const float*)d_in[11];
  const float* out_w = (const float*)d_in[12];
  const float* out_b = (const float*)d_in[13];
  const float* perturb = (const float*)d_in[14];
  const int* idx0 = (const int*)d_in[15];
  // d_in[16] = mask0 (bool) — unused; padding detected via idx==N
  const int* vslot0 = (const int*)d_in[18];
  const int* idx1 = (const int*)d_in[19];
  // d_in[20] = mask1 (bool) — unused
  const int* vslot1 = (const int*)d_in[22];
  const int total0 = in_sizes[15];
  const int total1 = in_sizes[19];

  // workspace layout (all buffers fully written before read every launch)
  char* wsb = (char*)d_ws;
  int* caps = (int*)wsb;                               // 2 ints
  float* h = (float*)(wsb + 256);                      // [N, C]
  float* lnbuf = h + (size_t)NVOX * CCH;               // [N, C] (also attn out)
  float* big = lnbuf + (size_t)NVOX * CCH;             // [N, 3C] qkv / [N, 4C] hid
  float* outb = (float*)d_out;                         // [N, 448], decoded in place

  cap_kernel<<<1, 256, 0, stream>>>(vslot0, vslot1, NVOX, caps);
  embed_kernel<<<(NVOX * CCH + 255) / 256, 256, 0, stream>>>(feats, coords, in_w, in_b, h);

  for (int i = 0; i < NBLK; ++i) {
    const int* idx = (i & 1) ? idx1 : idx0;
    const int* capP = (i & 1) ? caps + 1 : caps;
    const int total = (i & 1) ? total1 : total0;

    ln_kernel<<<NVOX, 256, 0, stream>>>(h, lnbuf, 1e-6f);
    gemm_kernel<0, 0><<<dim3(3 * CCH / 64, NVOX / 64), 256, 0, stream>>>(
        lnbuf, qkv_w + (size_t)i * CCH * 3 * CCH, qkv_b + (size_t)i * 3 * CCH, big,
        NVOX, 3 * CCH, CCH);
    attn_kernel<<<8192, 256, 0, stream>>>(big, idx, capP, total, lnbuf);
    gemm_kernel<0, 1><<<dim3(CCH / 64, NVOX / 64), 256, 0, stream>>>(
        lnbuf, proj_w + (size_t)i * CCH * CCH, proj_b + (size_t)i * CCH, h,
        NVOX, CCH, CCH);
    ln_kernel<<<NVOX, 256, 0, stream>>>(h, lnbuf, 1e-6f);
    gemm_kernel<1, 0><<<dim3(4 * CCH / 64, NVOX / 64), 256, 0, stream>>>(
        lnbuf, mlp_w1 + (size_t)i * CCH * 4 * CCH, mlp_b1 + (size_t)i * 4 * CCH, big,
        NVOX, 4 * CCH, CCH);
    gemm_kernel<0, 1><<<dim3(CCH / 64, NVOX / 64), 256, 0, stream>>>(
        big, mlp_w2 + (size_t)i * 4 * CCH * CCH, mlp_b2 + (size_t)i * CCH, h,
        NVOX, CCH, 4 * CCH);
  }

  ln_kernel<<<NVOX, 256, 0, stream>>>(h, lnbuf, 1e-5f);
  gemm_kernel<0, 0><<<dim3(OUT_CH / 64, NVOX / 64), 256, 0, stream>>>(
      lnbuf, out_w, out_b, outb, NVOX, OUT_CH, CCH);
  decode_kernel<<<NVOX, 256, 0, stream>>>(outb, coords, perturb);
}

// Round 2
// 7920.050 us; speedup vs baseline: 2.9018x; 2.9018x over previous
//
#include <hip/hip_runtime.h>
#include <math.h>

#define NVOX 8192
#define CCH 768
#define NH 12
#define DH 64
#define NBLK 12
#define NG 32
#define OUT_CH 448
#define OUT_PAD 512
#define CAPMAX 64

typedef __attribute__((ext_vector_type(8))) short v8s;
typedef __attribute__((ext_vector_type(4))) float v4f;

__device__ __forceinline__ unsigned short f2bf(float f) {
  unsigned u = __builtin_bit_cast(unsigned, f);
  u += 0x7fffu + ((u >> 16) & 1u);  // RNE
  return (unsigned short)(u >> 16);
}
__device__ __forceinline__ float bf2f(unsigned short b) {
  return __builtin_bit_cast(float, (unsigned)b << 16);
}

__device__ __forceinline__ void async16(const void* g, void* l) {
  __builtin_amdgcn_global_load_lds(
      (const __attribute__((address_space(1))) unsigned int*)g,
      (__attribute__((address_space(3))) unsigned int*)l, 16, 0, 0);
}

// ---------------------------------------------------------------------------
// prep: cap = max(vslot)+1 for both window configs
// ---------------------------------------------------------------------------
__global__ __launch_bounds__(256) void cap_kernel(const int* __restrict__ a,
                                                  const int* __restrict__ b,
                                                  int n, int* __restrict__ caps) {
  __shared__ int s0[256], s1[256];
  int m0 = 0, m1 = 0;
  for (int i = threadIdx.x; i < n; i += 256) {
    m0 = max(m0, a[i]);
    m1 = max(m1, b[i]);
  }
  s0[threadIdx.x] = m0;
  s1[threadIdx.x] = m1;
  __syncthreads();
  for (int st = 128; st > 0; st >>= 1) {
    if (threadIdx.x < st) {
      s0[threadIdx.x] = max(s0[threadIdx.x], s0[threadIdx.x + st]);
      s1[threadIdx.x] = max(s1[threadIdx.x], s1[threadIdx.x + st]);
    }
    __syncthreads();
  }
  if (threadIdx.x == 0) {
    caps[0] = s0[0] + 1;
    caps[1] = s1[0] + 1;
  }
}

// ---------------------------------------------------------------------------
// embed: h = feats @ in_w + in_b + pos_embed(coords)   (fp32 residual stream)
// ---------------------------------------------------------------------------
__global__ __launch_bounds__(256) void embed_kernel(const float* __restrict__ feats,
                                                    const int* __restrict__ coords,
                                                    const float* __restrict__ in_w,
                                                    const float* __restrict__ in_b,
                                                    float* __restrict__ h) {
  int id = blockIdx.x * 256 + threadIdx.x;
  if (id >= NVOX * CCH) return;
  int n = id / CCH, c = id - n * CCH;
  float acc = in_b[c];
#pragma unroll
  for (int k = 0; k < 8; ++k) acc += feats[n * 8 + k] * in_w[k * CCH + c];
  int axis = c / 256;
  int r = c - axis * 256;
  int f = r & 127;
  float freq = __expf(-(float)f * (9.210340371976184f / 128.0f));  // ln(10000)
  float phase = (float)coords[n * 3 + axis] * freq;
  acc += (r < 128) ? __sinf(phase) : __cosf(phase);
  h[id] = acc;
}

// ---------------------------------------------------------------------------
// layernorm (no affine) -> bf16 output (A-operand of following GEMM)
// ---------------------------------------------------------------------------
__global__ __launch_bounds__(256) void ln_kernel(const float* __restrict__ x,
                                                 unsigned short* __restrict__ y,
                                                 float eps) {
  int row = blockIdx.x;
  const float* xr = x + (size_t)row * CCH;
  float v[3];
  float s = 0.f, s2 = 0.f;
#pragma unroll
  for (int j = 0; j < 3; ++j) {
    v[j] = xr[threadIdx.x + j * 256];
    s += v[j];
    s2 += v[j] * v[j];
  }
#pragma unroll
  for (int off = 32; off >= 1; off >>= 1) {
    s += __shfl_xor(s, off, 64);
    s2 += __shfl_xor(s2, off, 64);
  }
  __shared__ float ss[4], ss2[4];
  int wave = threadIdx.x >> 6, lane = threadIdx.x & 63;
  if (lane == 0) { ss[wave] = s; ss2[wave] = s2; }
  __syncthreads();
  s = ss[0] + ss[1] + ss[2] + ss[3];
  s2 = ss2[0] + ss2[1] + ss2[2] + ss2[3];
  float mu = s * (1.0f / CCH);
  float var = s2 * (1.0f / CCH) - mu * mu;
  float rr = rsqrtf(var + eps);
  unsigned short* yr = y + (size_t)row * CCH;
#pragma unroll
  for (int j = 0; j < 3; ++j) yr[threadIdx.x + j * 256] = f2bf((v[j] - mu) * rr);
}

// ---------------------------------------------------------------------------
// weight convert: W fp32 [K][Nsrc] -> Wt bf16 [N][K] (transposed; n>=Nsrc -> 0)
// 64x64 tiles through LDS; both phases coalesced.
// ---------------------------------------------------------------------------
__global__ __launch_bounds__(256) void wconvert(const float* __restrict__ W,
                                                unsigned short* __restrict__ Wt,
                                                int K, int Nsrc) {
  __shared__ float t[64][65];
  int n0 = blockIdx.x * 64, k0 = blockIdx.y * 64;
  for (int e = threadIdx.x; e < 4096; e += 256) {
    int r = e >> 6, c = e & 63;  // k-row r, n-col c
    int n = n0 + c;
    t[r][c] = (n < Nsrc) ? W[(size_t)(k0 + r) * Nsrc + n] : 0.f;
  }
  __syncthreads();
  for (int e = threadIdx.x; e < 4096; e += 256) {
    int rn = e >> 6, ck = e & 63;
    Wt[(size_t)(n0 + rn) * K + k0 + ck] = f2bf(t[ck][rn]);
  }
}

// ---------------------------------------------------------------------------
// bf16 MFMA GEMM (m97 structure): out[M,Nn] = act(A[M,K] @ Bt[Nn,K]^T + bias)
// 128x128 tile, BK=32, 256 thr / 4 waves, each wave 64x64 = 4x4 MFMA 16x16x32.
// global_load_lds width 16 for staging; As/Bs row-major [tile_row][32] bf16.
// RES: fp32 read-modify-write into outf. OUTBF: bf16 store into outb.
// ---------------------------------------------------------------------------
__device__ __forceinline__ float gelu_exact(float x) {
  return 0.5f * x * (1.0f + erff(x * 0.70710678118654752f));
}

template <int ACT, int RES, int OUTBF>
__global__ __launch_bounds__(256) void gemm_mfma(const unsigned short* __restrict__ A,
                                                 const unsigned short* __restrict__ Bt,
                                                 const float* __restrict__ bias, int Nbias,
                                                 float* __restrict__ outf,
                                                 unsigned short* __restrict__ outb,
                                                 int Nn, int K) {
  __shared__ __align__(16) unsigned short As[128 * 32];
  __shared__ __align__(16) unsigned short Bs[128 * 32];
  const int tid = threadIdx.x;
  const int lane = tid & 63, w = tid >> 6;
  const int row0 = blockIdx.y * 128, col0 = blockIdx.x * 128;
  const int wm = (w >> 1) * 64, wn = (w & 1) * 64;  // wave origin in tile
  const int fm = lane & 15, fq = lane >> 4;

  // staging: chunk c (16B = 8 bf16) <-> tile row r = c>>2, k-chunk kc = c&3
  // lds dest for a wave's call is base + lane*16 == contiguous chunks
  const int c0 = w * 64 + lane;   // chunks 0..255
  const int c1 = c0 + 256;        // chunks 256..511
  const unsigned short* gA0 = A + (size_t)(row0 + (c0 >> 2)) * K + (c0 & 3) * 8;
  const unsigned short* gA1 = A + (size_t)(row0 + (c1 >> 2)) * K + (c1 & 3) * 8;
  const unsigned short* gB0 = Bt + (size_t)(col0 + (c0 >> 2)) * K + (c0 & 3) * 8;
  const unsigned short* gB1 = Bt + (size_t)(col0 + (c1 >> 2)) * K + (c1 & 3) * 8;
  unsigned short* lA0 = As + (size_t)(w * 64) * 8;
  unsigned short* lA1 = As + (size_t)(w * 64 + 256) * 8;
  unsigned short* lB0 = Bs + (size_t)(w * 64) * 8;
  unsigned short* lB1 = Bs + (size_t)(w * 64 + 256) * 8;

  v4f acc[4][4];
#pragma unroll
  for (int i = 0; i < 4; ++i)
#pragma unroll
    for (int j = 0; j < 4; ++j) acc[i][j] = (v4f){0.f, 0.f, 0.f, 0.f};

  for (int k0 = 0; k0 < K; k0 += 32) {
    async16(gA0 + k0, lA0);
    async16(gA1 + k0, lA1);
    async16(gB0 + k0, lB0);
    async16(gB1 + k0, lB1);
    __syncthreads();  // drains vmcnt(0) then barrier (compiler-inserted)
    v8s af[4], bf[4];
#pragma unroll
    for (int i = 0; i < 4; ++i)
      af[i] = *(const v8s*)(As + (size_t)(wm + i * 16 + fm) * 32 + fq * 8);
#pragma unroll
    for (int j = 0; j < 4; ++j)
      bf[j] = *(const v8s*)(Bs + (size_t)(wn + j * 16 + fm) * 32 + fq * 8);
#pragma unroll
    for (int i = 0; i < 4; ++i)
#pragma unroll
      for (int j = 0; j < 4; ++j)
        acc[i][j] = __builtin_amdgcn_mfma_f32_16x16x32_bf16(af[i], bf[j], acc[i][j], 0, 0, 0);
    __syncthreads();  // LDS free before next stage
  }

  // epilogue: D[row=quad*4+r][col=lane&15] per 16x16 tile
#pragma unroll
  for (int i = 0; i < 4; ++i) {
    int row = row0 + wm + i * 16 + fq * 4;
#pragma unroll
    for (int j = 0; j < 4; ++j) {
      int col = col0 + wn + j * 16 + fm;
      float b = (col < Nbias) ? bias[col] : 0.f;
#pragma unroll
      for (int r = 0; r < 4; ++r) {
        float v = acc[i][j][r] + b;
        if (ACT == 1) v = gelu_exact(v);
        size_t o = (size_t)(row + r) * Nn + col;
        if (RES) {
          outf[o] += v;
        } else if (OUTBF) {
          outb[o] = f2bf(v);
        } else {
          outf[o] = v;
        }
      }
    }
  }
}

// ---------------------------------------------------------------------------
// windowed attention (bf16 qkv in, bf16 out), fp32 math internally
// ---------------------------------------------------------------------------
__global__ __launch_bounds__(256) void attn_kernel(const unsigned short* __restrict__ qkv,
                                                   const int* __restrict__ idx,
                                                   const int* __restrict__ capPtr,
                                                   int total,
                                                   unsigned short* __restrict__ attn_out) {
  __shared__ float k_lds[CAPMAX][DH];
  __shared__ float v_lds[CAPMAX][DH];
  __shared__ int vox_lds[CAPMAX];
  const int cap = *capPtr;
  if (cap > CAPMAX) return;
  const int nw = total / cap;
  const int tasks = nw * NH;
  const int tid = threadIdx.x;
  const int wave = tid >> 6, lane = tid & 63;
  for (int task = blockIdx.x; task < tasks; task += gridDim.x) {
    const int w = task / NH, hh = task - w * NH;
    if (tid < cap) vox_lds[tid] = idx[w * cap + tid];
    __syncthreads();
    for (int e = tid; e < cap * DH; e += 256) {
      int s = e >> 6, d = e & 63;
      int vox = vox_lds[s];
      float kv = 0.f, vv = 0.f;
      if (vox < NVOX) {
        const unsigned short* base = qkv + (size_t)vox * (3 * CCH) + hh * DH + d;
        kv = bf2f(base[CCH]);
        vv = bf2f(base[2 * CCH]);
      }
      k_lds[s][d] = kv;
      v_lds[s][d] = vv;
    }
    __syncthreads();
    for (int s = wave; s < cap; s += 4) {
      int vox = vox_lds[s];
      if (vox < NVOX) {
        float qv = bf2f(qkv[(size_t)vox * (3 * CCH) + hh * DH + lane]) * 0.125f;
        float myscore = -1e30f;
        for (int j = 0; j < cap; ++j) {
          float p = qv * k_lds[j][lane];
#pragma unroll
          for (int off = 32; off >= 1; off >>= 1) p += __shfl_xor(p, off, 64);
          if (lane == j && vox_lds[j] < NVOX) myscore = p;
        }
        float m = myscore;
#pragma unroll
        for (int off = 32; off >= 1; off >>= 1) m = fmaxf(m, __shfl_xor(m, off, 64));
        float e = (myscore > -1e29f) ? __expf(myscore - m) : 0.f;
        float den = e;
#pragma unroll
        for (int off = 32; off >= 1; off >>= 1) den += __shfl_xor(den, off, 64);
        float p = e / den;
        float o = 0.f;
        for (int j = 0; j < cap; ++j) {
          float pj = __shfl(p, j, 64);
          o = fmaf(pj, v_lds[j][lane], o);
        }
        attn_out[(size_t)vox * CCH + hh * DH + lane] = f2bf(o);
      }
    }
    __syncthreads();
  }
}

// ---------------------------------------------------------------------------
// gaussian decode: reads padded [N][512] fp32, writes d_out [N][448]
// ---------------------------------------------------------------------------
__global__ __launch_bounds__(256) void decode_kernel(const float* __restrict__ outpad,
                                                     const int* __restrict__ coords,
                                                     const float* __restrict__ perturb,
                                                     float* __restrict__ out) {
  __shared__ float row[OUT_CH];
  const int n = blockIdx.x;
  const float* src = outpad + (size_t)n * OUT_PAD;
  for (int e = threadIdx.x; e < OUT_CH; e += 256) row[e] = src[e];
  __syncthreads();
  float* o = out + (size_t)n * OUT_CH;
  for (int e = threadIdx.x; e < OUT_CH; e += 256) {
    int g = e / 14, j = e - g * 14;
    float v;
    if (j < 3) {
      float xyz = ((float)coords[n * 3 + j] + 0.5f) * (1.0f / 64.0f);
      v = xyz + tanhf(row[g * 3 + j] + perturb[g * 3 + j]) * (0.75f / 64.0f);
    } else if (j < 6) {
      v = row[96 + g * 3 + (j - 3)];
    } else if (j < 9) {
      v = row[192 + g * 3 + (j - 6)];
    } else if (j < 13) {
      v = row[288 + g * 4 + (j - 9)] * 0.1f;
    } else {
      v = row[416 + g];
    }
    o[e] = v;
  }
}

// ---------------------------------------------------------------------------
extern "C" void kernel_launch(void* const* d_in, const int* in_sizes, int n_in,
                              void* d_out, int out_size, void* d_ws, size_t ws_size,
                              hipStream_t stream) {
  const float* feats = (const float*)d_in[0];
  const int* coords = (const int*)d_in[1];
  const float* in_w = (const float*)d_in[2];
  const float* in_b = (const float*)d_in[3];
  const float* qkv_w = (const float*)d_in[4];
  const float* qkv_b = (const float*)d_in[5];
  const float* proj_w = (const float*)d_in[6];
  const float* proj_b = (const float*)d_in[7];
  const float* mlp_w1 = (const float*)d_in[8];
  const float* mlp_b1 = (const float*)d_in[9];
  const float* mlp_w2 = (const float*)d_in[10];
  const float* mlp_b2 = (const float*)d_in[11];
  const float* out_w = (const float*)d_in[12];
  const float* out_b = (const float*)d_in[13];
  const float* perturb = (const float*)d_in[14];
  const int* idx0 = (const int*)d_in[15];
  const int* vslot0 = (const int*)d_in[18];
  const int* idx1 = (const int*)d_in[19];
  const int* vslot1 = (const int*)d_in[22];
  const int total0 = in_sizes[15];
  const int total1 = in_sizes[19];

  // workspace layout (bytes): everything fully rewritten each launch
  char* p = (char*)d_ws;
  int* caps = (int*)p;                                                    // 256 B
  float* h = (float*)(p + 256);                                           // 25165824
  unsigned short* abuf = (unsigned short*)(p + 256 + 25165824);           // 12582912
  unsigned short* big = (unsigned short*)(p + 256 + 37748736);            // 50331648
  unsigned short* wst = (unsigned short*)(p + 256 + 88080384);            // 14155776
  float* outpad = (float*)(p + 256 + 102236160);                          // 16777216
  // weight-staging element offsets
  const size_t OQ = 0;
  const size_t OP = (size_t)768 * 2304;
  const size_t OM1 = OP + (size_t)768 * 768;
  const size_t OM2 = OM1 + (size_t)768 * 3072;

  cap_kernel<<<1, 256, 0, stream>>>(vslot0, vslot1, NVOX, caps);
  embed_kernel<<<(NVOX * CCH + 255) / 256, 256, 0, stream>>>(feats, coords, in_w, in_b, h);

  for (int i = 0; i < NBLK; ++i) {
    const int* idx = (i & 1) ? idx1 : idx0;
    const int* capP = (i & 1) ? caps + 1 : caps;
    const int total = (i & 1) ? total1 : total0;

    // convert this block's 4 weights -> bf16 transposed [N][K]
    wconvert<<<dim3(36, 12), 256, 0, stream>>>(qkv_w + (size_t)i * 768 * 2304, wst + OQ, 768, 2304);
    wconvert<<<dim3(12, 12), 256, 0, stream>>>(proj_w + (size_t)i * 768 * 768, wst + OP, 768, 768);
    wconvert<<<dim3(48, 12), 256, 0, stream>>>(mlp_w1 + (size_t)i * 768 * 3072, wst + OM1, 768, 3072);
    wconvert<<<dim3(12, 48), 256, 0, stream>>>(mlp_w2 + (size_t)i * 3072 * 768, wst + OM2, 3072, 768);

    ln_kernel<<<NVOX, 256, 0, stream>>>(h, abuf, 1e-6f);
    gemm_mfma<0, 0, 1><<<dim3(18, 64), 256, 0, stream>>>(
        abuf, wst + OQ, qkv_b + (size_t)i * 2304, 2304, nullptr, big, 2304, 768);
    attn_kernel<<<8192, 256, 0, stream>>>(big, idx, capP, total, abuf);
    gemm_mfma<0, 1, 0><<<dim3(6, 64), 256, 0, stream>>>(
        abuf, wst + OP, proj_b + (size_t)i * 768, 768, h, nullptr, 768, 768);
    ln_kernel<<<NVOX, 256, 0, stream>>>(h, abuf, 1e-6f);
    gemm_mfma<1, 0, 1><<<dim3(24, 64), 256, 0, stream>>>(
        abuf, wst + OM1, mlp_b1 + (size_t)i * 3072, 3072, nullptr, big, 3072, 768);
    gemm_mfma<0, 1, 0><<<dim3(6, 64), 256, 0, stream>>>(
        big, wst + OM2, mlp_b2 + (size_t)i * 768, 768, h, nullptr, 768, 3072);
  }

  ln_kernel<<<NVOX, 256, 0, stream>>>(h, abuf, 1e-5f);
  wconvert<<<dim3(8, 12), 256, 0, stream>>>(out_w, wst + OQ, 768, OUT_CH);  // pad N->512
  gemm_mfma<0, 0, 0><<<dim3(4, 64), 256, 0, stream>>>(
      abuf, wst + OQ, out_b, OUT_CH, outpad, nullptr, OUT_PAD, 768);
  decode_kernel<<<NVOX, 256, 0, stream>>>(outpad, coords, perturb, (float*)d_out);
}

// Round 3
// 5849.606 us; speedup vs baseline: 3.9289x; 1.3539x over previous
//
#include <hip/hip_runtime.h>
#include <math.h>

#define NVOX 8192
#define CCH 768
#define NH 12
#define DH 64
#define NBLK 12
#define NG 32
#define OUT_CH 448
#define OUT_PAD 512
#define CAP 48

typedef __attribute__((ext_vector_type(8))) short v8s;
typedef __attribute__((ext_vector_type(4))) float v4f;

__device__ __forceinline__ unsigned short f2bf(float f) {
  unsigned u = __builtin_bit_cast(unsigned, f);
  u += 0x7fffu + ((u >> 16) & 1u);  // RNE
  return (unsigned short)(u >> 16);
}
__device__ __forceinline__ float bf2f(unsigned short b) {
  return __builtin_bit_cast(float, (unsigned)b << 16);
}

__device__ __forceinline__ void async16(const void* g, void* l) {
  __builtin_amdgcn_global_load_lds(
      (const __attribute__((address_space(1))) unsigned int*)g,
      (__attribute__((address_space(3))) unsigned int*)l, 16, 0, 0);
}

// ---------------------------------------------------------------------------
// prep: cap = max(vslot)+1 for both window configs
// ---------------------------------------------------------------------------
__global__ __launch_bounds__(256) void cap_kernel(const int* __restrict__ a,
                                                  const int* __restrict__ b,
                                                  int n, int* __restrict__ caps) {
  __shared__ int s0[256], s1[256];
  int m0 = 0, m1 = 0;
  for (int i = threadIdx.x; i < n; i += 256) {
    m0 = max(m0, a[i]);
    m1 = max(m1, b[i]);
  }
  s0[threadIdx.x] = m0;
  s1[threadIdx.x] = m1;
  __syncthreads();
  for (int st = 128; st > 0; st >>= 1) {
    if (threadIdx.x < st) {
      s0[threadIdx.x] = max(s0[threadIdx.x], s0[threadIdx.x + st]);
      s1[threadIdx.x] = max(s1[threadIdx.x], s1[threadIdx.x + st]);
    }
    __syncthreads();
  }
  if (threadIdx.x == 0) {
    caps[0] = s0[0] + 1;
    caps[1] = s1[0] + 1;
  }
}

// ---------------------------------------------------------------------------
// embed: h = feats @ in_w + in_b + pos_embed(coords)   (fp32 residual stream)
// ---------------------------------------------------------------------------
__global__ __launch_bounds__(256) void embed_kernel(const float* __restrict__ feats,
                                                    const int* __restrict__ coords,
                                                    const float* __restrict__ in_w,
                                                    const float* __restrict__ in_b,
                                                    float* __restrict__ h) {
  int id = blockIdx.x * 256 + threadIdx.x;
  if (id >= NVOX * CCH) return;
  int n = id / CCH, c = id - n * CCH;
  float acc = in_b[c];
#pragma unroll
  for (int k = 0; k < 8; ++k) acc += feats[n * 8 + k] * in_w[k * CCH + c];
  int axis = c / 256;
  int r = c - axis * 256;
  int f = r & 127;
  float freq = __expf(-(float)f * (9.210340371976184f / 128.0f));  // ln(10000)
  float phase = (float)coords[n * 3 + axis] * freq;
  acc += (r < 128) ? __sinf(phase) : __cosf(phase);
  h[id] = acc;
}

// ---------------------------------------------------------------------------
// layernorm (no affine) -> bf16 output (A-operand of following GEMM)
// ---------------------------------------------------------------------------
__global__ __launch_bounds__(256) void ln_kernel(const float* __restrict__ x,
                                                 unsigned short* __restrict__ y,
                                                 float eps) {
  int row = blockIdx.x;
  const float* xr = x + (size_t)row * CCH;
  float v[3];
  float s = 0.f, s2 = 0.f;
#pragma unroll
  for (int j = 0; j < 3; ++j) {
    v[j] = xr[threadIdx.x + j * 256];
    s += v[j];
    s2 += v[j] * v[j];
  }
#pragma unroll
  for (int off = 32; off >= 1; off >>= 1) {
    s += __shfl_xor(s, off, 64);
    s2 += __shfl_xor(s2, off, 64);
  }
  __shared__ float ss[4], ss2[4];
  int wave = threadIdx.x >> 6, lane = threadIdx.x & 63;
  if (lane == 0) { ss[wave] = s; ss2[wave] = s2; }
  __syncthreads();
  s = ss[0] + ss[1] + ss[2] + ss[3];
  s2 = ss2[0] + ss2[1] + ss2[2] + ss2[3];
  float mu = s * (1.0f / CCH);
  float var = s2 * (1.0f / CCH) - mu * mu;
  float rr = rsqrtf(var + eps);
  unsigned short* yr = y + (size_t)row * CCH;
#pragma unroll
  for (int j = 0; j < 3; ++j) yr[threadIdx.x + j * 256] = f2bf((v[j] - mu) * rr);
}

// ---------------------------------------------------------------------------
// weight convert: W fp32 [K][Nsrc] -> Wt bf16 [N][K] (transposed; n>=Nsrc -> 0)
// ---------------------------------------------------------------------------
__global__ __launch_bounds__(256) void wconvert(const float* __restrict__ W,
                                                unsigned short* __restrict__ Wt,
                                                int K, int Nsrc) {
  __shared__ float t[64][65];
  int n0 = blockIdx.x * 64, k0 = blockIdx.y * 64;
  for (int e = threadIdx.x; e < 4096; e += 256) {
    int r = e >> 6, c = e & 63;  // k-row r, n-col c
    int n = n0 + c;
    t[r][c] = (n < Nsrc) ? W[(size_t)(k0 + r) * Nsrc + n] : 0.f;
  }
  __syncthreads();
  for (int e = threadIdx.x; e < 4096; e += 256) {
    int rn = e >> 6, ck = e & 63;
    Wt[(size_t)(n0 + rn) * K + k0 + ck] = f2bf(t[ck][rn]);
  }
}

// ---------------------------------------------------------------------------
// bf16 MFMA GEMM (m97 structure): out[M,Nn] = act(A[M,K] @ Bt[Nn,K]^T + bias)
// ---------------------------------------------------------------------------
__device__ __forceinline__ float gelu_exact(float x) {
  return 0.5f * x * (1.0f + erff(x * 0.70710678118654752f));
}

template <int ACT, int RES, int OUTBF>
__global__ __launch_bounds__(256) void gemm_mfma(const unsigned short* __restrict__ A,
                                                 const unsigned short* __restrict__ Bt,
                                                 const float* __restrict__ bias, int Nbias,
                                                 float* __restrict__ outf,
                                                 unsigned short* __restrict__ outb,
                                                 int Nn, int K) {
  __shared__ __align__(16) unsigned short As[128 * 32];
  __shared__ __align__(16) unsigned short Bs[128 * 32];
  const int tid = threadIdx.x;
  const int lane = tid & 63, w = tid >> 6;
  const int row0 = blockIdx.y * 128, col0 = blockIdx.x * 128;
  const int wm = (w >> 1) * 64, wn = (w & 1) * 64;
  const int fm = lane & 15, fq = lane >> 4;

  const int c0 = w * 64 + lane;
  const int c1 = c0 + 256;
  const unsigned short* gA0 = A + (size_t)(row0 + (c0 >> 2)) * K + (c0 & 3) * 8;
  const unsigned short* gA1 = A + (size_t)(row0 + (c1 >> 2)) * K + (c1 & 3) * 8;
  const unsigned short* gB0 = Bt + (size_t)(col0 + (c0 >> 2)) * K + (c0 & 3) * 8;
  const unsigned short* gB1 = Bt + (size_t)(col0 + (c1 >> 2)) * K + (c1 & 3) * 8;
  unsigned short* lA0 = As + (size_t)(w * 64) * 8;
  unsigned short* lA1 = As + (size_t)(w * 64 + 256) * 8;
  unsigned short* lB0 = Bs + (size_t)(w * 64) * 8;
  unsigned short* lB1 = Bs + (size_t)(w * 64 + 256) * 8;

  v4f acc[4][4];
#pragma unroll
  for (int i = 0; i < 4; ++i)
#pragma unroll
    for (int j = 0; j < 4; ++j) acc[i][j] = (v4f){0.f, 0.f, 0.f, 0.f};

  for (int k0 = 0; k0 < K; k0 += 32) {
    async16(gA0 + k0, lA0);
    async16(gA1 + k0, lA1);
    async16(gB0 + k0, lB0);
    async16(gB1 + k0, lB1);
    __syncthreads();
    v8s af[4], bf[4];
#pragma unroll
    for (int i = 0; i < 4; ++i)
      af[i] = *(const v8s*)(As + (size_t)(wm + i * 16 + fm) * 32 + fq * 8);
#pragma unroll
    for (int j = 0; j < 4; ++j)
      bf[j] = *(const v8s*)(Bs + (size_t)(wn + j * 16 + fm) * 32 + fq * 8);
#pragma unroll
    for (int i = 0; i < 4; ++i)
#pragma unroll
      for (int j = 0; j < 4; ++j)
        acc[i][j] = __builtin_amdgcn_mfma_f32_16x16x32_bf16(af[i], bf[j], acc[i][j], 0, 0, 0);
    __syncthreads();
  }

#pragma unroll
  for (int i = 0; i < 4; ++i) {
    int row = row0 + wm + i * 16 + fq * 4;
#pragma unroll
    for (int j = 0; j < 4; ++j) {
      int col = col0 + wn + j * 16 + fm;
      float b = (col < Nbias) ? bias[col] : 0.f;
#pragma unroll
      for (int r = 0; r < 4; ++r) {
        float v = acc[i][j][r] + b;
        if (ACT == 1) v = gelu_exact(v);
        size_t o = (size_t)(row + r) * Nn + col;
        if (RES) {
          outf[o] += v;
        } else if (OUTBF) {
          outb[o] = f2bf(v);
        } else {
          outf[o] = v;
        }
      }
    }
  }
}

// ---------------------------------------------------------------------------
// windowed attention: one wave per (window, head); lane = query index.
// No cross-lane reductions: K/V broadcast from LDS, per-lane softmax via p_lds.
// ---------------------------------------------------------------------------
__global__ __launch_bounds__(64) void attn_kernel(const unsigned short* __restrict__ qkv,
                                                  const int* __restrict__ idx,
                                                  const int* __restrict__ capPtr,
                                                  int total,
                                                  unsigned short* __restrict__ attn_out) {
  __shared__ float k_lds[CAP][DH];       // [j][d]
  __shared__ float v_lds[CAP][DH];       // [j][d]
  __shared__ float p_lds[64][CAP + 1];   // [i][j], stride 49 -> conflict-free
  __shared__ int vox_lds[64];
  const int cap = *capPtr;
  if (cap > CAP) return;  // loud failure (validation) rather than OOB
  const int nw = total / cap;
  const int tasks = nw * NH;
  const int lane = threadIdx.x;
  for (int task = blockIdx.x; task < tasks; task += gridDim.x) {
    const int w = task / NH, hh = task - w * NH;
    int vox_i = NVOX;
    if (lane < cap) vox_i = idx[w * cap + lane];
    vox_lds[lane] = vox_i;
    __syncthreads();
    // stage K,V fp32, coalesced (lane = d)
    for (int j = 0; j < cap; ++j) {
      int vj = vox_lds[j];
      float kv = 0.f, vv = 0.f;
      if (vj < NVOX) {
        const unsigned short* b = qkv + (size_t)vj * (3 * CCH) + CCH + hh * DH + lane;
        kv = bf2f(b[0]);
        vv = bf2f(b[CCH]);
      }
      k_lds[j][lane] = kv;
      v_lds[j][lane] = vv;
    }
    __syncthreads();
    const bool active = (lane < cap) && (vox_i < NVOX);
    float q[DH];
    if (active) {
      const unsigned short* qb = qkv + (size_t)vox_i * (3 * CCH) + hh * DH;
#pragma unroll
      for (int c = 0; c < 8; ++c) {
        v8s t = *(const v8s*)(qb + c * 8);
#pragma unroll
        for (int e = 0; e < 8; ++e)
          q[c * 8 + e] = bf2f((unsigned short)t[e]) * 0.125f;  // fold 1/sqrt(DH)
      }
    } else {
#pragma unroll
      for (int d = 0; d < DH; ++d) q[d] = 0.f;
    }
    // scores: s_ij = q_i . k_j   (K broadcast; 4 partial sums break the chain)
    float m = -1e30f;
    for (int j = 0; j < cap; ++j) {
      const float4* kr = (const float4*)k_lds[j];
      float s0 = 0.f, s1 = 0.f, s2 = 0.f, s3 = 0.f;
#pragma unroll
      for (int c = 0; c < 16; ++c) {
        float4 k4 = kr[c];
        s0 = fmaf(q[4 * c + 0], k4.x, s0);
        s1 = fmaf(q[4 * c + 1], k4.y, s1);
        s2 = fmaf(q[4 * c + 2], k4.z, s2);
        s3 = fmaf(q[4 * c + 3], k4.w, s3);
      }
      float s = (s0 + s1) + (s2 + s3);
      if (vox_lds[j] >= NVOX) s = -1e9f;
      p_lds[lane][j] = s;
      m = fmaxf(m, s);
    }
    float den = 0.f;
    for (int j = 0; j < cap; ++j) {
      float e = __expf(p_lds[lane][j] - m);
      p_lds[lane][j] = e;
      den += e;
    }
    float rden = 1.0f / den;
    // output: o_i = sum_j p_ij v_j  (V broadcast)
    float o[DH];
#pragma unroll
    for (int d = 0; d < DH; ++d) o[d] = 0.f;
    for (int j = 0; j < cap; ++j) {
      float pj = p_lds[lane][j];
      const float4* vr = (const float4*)v_lds[j];
#pragma unroll
      for (int c = 0; c < 16; ++c) {
        float4 v4 = vr[c];
        o[4 * c + 0] = fmaf(pj, v4.x, o[4 * c + 0]);
        o[4 * c + 1] = fmaf(pj, v4.y, o[4 * c + 1]);
        o[4 * c + 2] = fmaf(pj, v4.z, o[4 * c + 2]);
        o[4 * c + 3] = fmaf(pj, v4.w, o[4 * c + 3]);
      }
    }
    if (active) {
      unsigned short* ob = attn_out + (size_t)vox_i * CCH + hh * DH;
#pragma unroll
      for (int c = 0; c < 8; ++c) {
        v8s t;
#pragma unroll
        for (int e = 0; e < 8; ++e) t[e] = (short)f2bf(o[c * 8 + e] * rden);
        *(v8s*)(ob + c * 8) = t;
      }
    }
    __syncthreads();
  }
}

// ---------------------------------------------------------------------------
// gaussian decode: reads padded [N][512] fp32, writes d_out [N][448]
// ---------------------------------------------------------------------------
__global__ __launch_bounds__(256) void decode_kernel(const float* __restrict__ outpad,
                                                     const int* __restrict__ coords,
                                                     const float* __restrict__ perturb,
                                                     float* __restrict__ out) {
  __shared__ float row[OUT_CH];
  const int n = blockIdx.x;
  const float* src = outpad + (size_t)n * OUT_PAD;
  for (int e = threadIdx.x; e < OUT_CH; e += 256) row[e] = src[e];
  __syncthreads();
  float* o = out + (size_t)n * OUT_CH;
  for (int e = threadIdx.x; e < OUT_CH; e += 256) {
    int g = e / 14, j = e - g * 14;
    float v;
    if (j < 3) {
      float xyz = ((float)coords[n * 3 + j] + 0.5f) * (1.0f / 64.0f);
      v = xyz + tanhf(row[g * 3 + j] + perturb[g * 3 + j]) * (0.75f / 64.0f);
    } else if (j < 6) {
      v = row[96 + g * 3 + (j - 3)];
    } else if (j < 9) {
      v = row[192 + g * 3 + (j - 6)];
    } else if (j < 13) {
      v = row[288 + g * 4 + (j - 9)] * 0.1f;
    } else {
      v = row[416 + g];
    }
    o[e] = v;
  }
}

// ---------------------------------------------------------------------------
extern "C" void kernel_launch(void* const* d_in, const int* in_sizes, int n_in,
                              void* d_out, int out_size, void* d_ws, size_t ws_size,
                              hipStream_t stream) {
  const float* feats = (const float*)d_in[0];
  const int* coords = (const int*)d_in[1];
  const float* in_w = (const float*)d_in[2];
  const float* in_b = (const float*)d_in[3];
  const float* qkv_w = (const float*)d_in[4];
  const float* qkv_b = (const float*)d_in[5];
  const float* proj_w = (const float*)d_in[6];
  const float* proj_b = (const float*)d_in[7];
  const float* mlp_w1 = (const float*)d_in[8];
  const float* mlp_b1 = (const float*)d_in[9];
  const float* mlp_w2 = (const float*)d_in[10];
  const float* mlp_b2 = (const float*)d_in[11];
  const float* out_w = (const float*)d_in[12];
  const float* out_b = (const float*)d_in[13];
  const float* perturb = (const float*)d_in[14];
  const int* idx0 = (const int*)d_in[15];
  const int* vslot0 = (const int*)d_in[18];
  const int* idx1 = (const int*)d_in[19];
  const int* vslot1 = (const int*)d_in[22];
  const int total0 = in_sizes[15];
  const int total1 = in_sizes[19];

  char* p = (char*)d_ws;
  int* caps = (int*)p;                                                    // 256 B
  float* h = (float*)(p + 256);                                           // 25165824
  unsigned short* abuf = (unsigned short*)(p + 256 + 25165824);           // 12582912
  unsigned short* big = (unsigned short*)(p + 256 + 37748736);            // 50331648
  unsigned short* wst = (unsigned short*)(p + 256 + 88080384);            // 14155776
  float* outpad = (float*)(p + 256 + 102236160);                          // 16777216
  const size_t OQ = 0;
  const size_t OP = (size_t)768 * 2304;
  const size_t OM1 = OP + (size_t)768 * 768;
  const size_t OM2 = OM1 + (size_t)768 * 3072;

  cap_kernel<<<1, 256, 0, stream>>>(vslot0, vslot1, NVOX, caps);
  embed_kernel<<<(NVOX * CCH + 255) / 256, 256, 0, stream>>>(feats, coords, in_w, in_b, h);

  for (int i = 0; i < NBLK; ++i) {
    const int* idx = (i & 1) ? idx1 : idx0;
    const int* capP = (i & 1) ? caps + 1 : caps;
    const int total = (i & 1) ? total1 : total0;

    wconvert<<<dim3(36, 12), 256, 0, stream>>>(qkv_w + (size_t)i * 768 * 2304, wst + OQ, 768, 2304);
    wconvert<<<dim3(12, 12), 256, 0, stream>>>(proj_w + (size_t)i * 768 * 768, wst + OP, 768, 768);
    wconvert<<<dim3(48, 12), 256, 0, stream>>>(mlp_w1 + (size_t)i * 768 * 3072, wst + OM1, 768, 3072);
    wconvert<<<dim3(12, 48), 256, 0, stream>>>(mlp_w2 + (size_t)i * 3072 * 768, wst + OM2, 3072, 768);

    ln_kernel<<<NVOX, 256, 0, stream>>>(h, abuf, 1e-6f);
    gemm_mfma<0, 0, 1><<<dim3(18, 64), 256, 0, stream>>>(
        abuf, wst + OQ, qkv_b + (size_t)i * 2304, 2304, nullptr, big, 2304, 768);
    attn_kernel<<<4096, 64, 0, stream>>>(big, idx, capP, total, abuf);
    gemm_mfma<0, 1, 0><<<dim3(6, 64), 256, 0, stream>>>(
        abuf, wst + OP, proj_b + (size_t)i * 768, 768, h, nullptr, 768, 768);
    ln_kernel<<<NVOX, 256, 0, stream>>>(h, abuf, 1e-6f);
    gemm_mfma<1, 0, 1><<<dim3(24, 64), 256, 0, stream>>>(
        abuf, wst + OM1, mlp_b1 + (size_t)i * 3072, 3072, nullptr, big, 3072, 768);
    gemm_mfma<0, 1, 0><<<dim3(6, 64), 256, 0, stream>>>(
        big, wst + OM2, mlp_b2 + (size_t)i * 768, 768, h, nullptr, 768, 3072);
  }

  ln_kernel<<<NVOX, 256, 0, stream>>>(h, abuf, 1e-5f);
  wconvert<<<dim3(8, 12), 256, 0, stream>>>(out_w, wst + OQ, 768, OUT_CH);
  gemm_mfma<0, 0, 0><<<dim3(4, 64), 256, 0, stream>>>(
      abuf, wst + OQ, out_b, OUT_CH, outpad, nullptr, OUT_PAD, 768);
  decode_kernel<<<NVOX, 256, 0, stream>>>(outpad, coords, perturb, (float*)d_out);
}

// Round 4
// 4533.014 us; speedup vs baseline: 5.0700x; 1.2904x over previous
//
#include <hip/hip_runtime.h>
#include <math.h>

#define NVOX 8192
#define CCH 768
#define NH 12
#define DH 64
#define NBLK 12
#define NG 32
#define OUT_CH 448
#define OUT_PAD 512
#define CAP 48
#define APITCH 72  // LDS row pitch (bf16) for Q/K/P/Vt: 144 B rows, 16B-aligned

typedef __attribute__((ext_vector_type(8))) short v8s;
typedef __attribute__((ext_vector_type(4))) float v4f;

__device__ __forceinline__ unsigned short f2bf(float f) {
  unsigned u = __builtin_bit_cast(unsigned, f);
  u += 0x7fffu + ((u >> 16) & 1u);  // RNE
  return (unsigned short)(u >> 16);
}
__device__ __forceinline__ float bf2f(unsigned short b) {
  return __builtin_bit_cast(float, (unsigned)b << 16);
}

__device__ __forceinline__ void async16(const void* g, void* l) {
  __builtin_amdgcn_global_load_lds(
      (const __attribute__((address_space(1))) unsigned int*)g,
      (__attribute__((address_space(3))) unsigned int*)l, 16, 0, 0);
}

// ---------------------------------------------------------------------------
// prep: cap = max(vslot)+1 for both window configs
// ---------------------------------------------------------------------------
__global__ __launch_bounds__(256) void cap_kernel(const int* __restrict__ a,
                                                  const int* __restrict__ b,
                                                  int n, int* __restrict__ caps) {
  __shared__ int s0[256], s1[256];
  int m0 = 0, m1 = 0;
  for (int i = threadIdx.x; i < n; i += 256) {
    m0 = max(m0, a[i]);
    m1 = max(m1, b[i]);
  }
  s0[threadIdx.x] = m0;
  s1[threadIdx.x] = m1;
  __syncthreads();
  for (int st = 128; st > 0; st >>= 1) {
    if (threadIdx.x < st) {
      s0[threadIdx.x] = max(s0[threadIdx.x], s0[threadIdx.x + st]);
      s1[threadIdx.x] = max(s1[threadIdx.x], s1[threadIdx.x + st]);
    }
    __syncthreads();
  }
  if (threadIdx.x == 0) {
    caps[0] = s0[0] + 1;
    caps[1] = s1[0] + 1;
  }
}

// ---------------------------------------------------------------------------
// embed: h = feats @ in_w + in_b + pos_embed(coords)   (fp32 residual stream)
// ---------------------------------------------------------------------------
__global__ __launch_bounds__(256) void embed_kernel(const float* __restrict__ feats,
                                                    const int* __restrict__ coords,
                                                    const float* __restrict__ in_w,
                                                    const float* __restrict__ in_b,
                                                    float* __restrict__ h) {
  int id = blockIdx.x * 256 + threadIdx.x;
  if (id >= NVOX * CCH) return;
  int n = id / CCH, c = id - n * CCH;
  float acc = in_b[c];
#pragma unroll
  for (int k = 0; k < 8; ++k) acc += feats[n * 8 + k] * in_w[k * CCH + c];
  int axis = c / 256;
  int r = c - axis * 256;
  int f = r & 127;
  float freq = __expf(-(float)f * (9.210340371976184f / 128.0f));  // ln(10000)
  float phase = (float)coords[n * 3 + axis] * freq;
  acc += (r < 128) ? __sinf(phase) : __cosf(phase);
  h[id] = acc;
}

// ---------------------------------------------------------------------------
// layernorm (no affine) -> bf16 output (A-operand of following GEMM)
// ---------------------------------------------------------------------------
__global__ __launch_bounds__(256) void ln_kernel(const float* __restrict__ x,
                                                 unsigned short* __restrict__ y,
                                                 float eps) {
  int row = blockIdx.x;
  const float* xr = x + (size_t)row * CCH;
  float v[3];
  float s = 0.f, s2 = 0.f;
#pragma unroll
  for (int j = 0; j < 3; ++j) {
    v[j] = xr[threadIdx.x + j * 256];
    s += v[j];
    s2 += v[j] * v[j];
  }
#pragma unroll
  for (int off = 32; off >= 1; off >>= 1) {
    s += __shfl_xor(s, off, 64);
    s2 += __shfl_xor(s2, off, 64);
  }
  __shared__ float ss[4], ss2[4];
  int wave = threadIdx.x >> 6, lane = threadIdx.x & 63;
  if (lane == 0) { ss[wave] = s; ss2[wave] = s2; }
  __syncthreads();
  s = ss[0] + ss[1] + ss[2] + ss[3];
  s2 = ss2[0] + ss2[1] + ss2[2] + ss2[3];
  float mu = s * (1.0f / CCH);
  float var = s2 * (1.0f / CCH) - mu * mu;
  float rr = rsqrtf(var + eps);
  unsigned short* yr = y + (size_t)row * CCH;
#pragma unroll
  for (int j = 0; j < 3; ++j) yr[threadIdx.x + j * 256] = f2bf((v[j] - mu) * rr);
}

// ---------------------------------------------------------------------------
// weight convert: W fp32 [K][Nsrc] -> Wt bf16 [N][K] (transposed; n>=Nsrc -> 0)
// ---------------------------------------------------------------------------
__device__ __forceinline__ void wconv_tile(const float* __restrict__ W,
                                           unsigned short* __restrict__ Wt,
                                           int K, int Nsrc, int nt, int kt,
                                           float (*t)[65]) {
  int n0 = nt * 64, k0 = kt * 64;
  for (int e = threadIdx.x; e < 4096; e += 256) {
    int r = e >> 6, c = e & 63;
    int n = n0 + c;
    t[r][c] = (n < Nsrc) ? W[(size_t)(k0 + r) * Nsrc + n] : 0.f;
  }
  __syncthreads();
  for (int e = threadIdx.x; e < 4096; e += 256) {
    int rn = e >> 6, ck = e & 63;
    Wt[(size_t)(n0 + rn) * K + k0 + ck] = f2bf(t[ck][rn]);
  }
}

__global__ __launch_bounds__(256) void wconvert(const float* __restrict__ W,
                                                unsigned short* __restrict__ Wt,
                                                int K, int Nsrc) {
  __shared__ float t[64][65];
  wconv_tile(W, Wt, K, Nsrc, blockIdx.x, blockIdx.y, t);
}

// fused: all 4 weights of one block in one launch (1728 tiles)
__global__ __launch_bounds__(256) void wconvert4(const float* __restrict__ W0,
                                                 const float* __restrict__ W1,
                                                 const float* __restrict__ W2,
                                                 const float* __restrict__ W3,
                                                 unsigned short* __restrict__ D0,
                                                 unsigned short* __restrict__ D1,
                                                 unsigned short* __restrict__ D2,
                                                 unsigned short* __restrict__ D3) {
  __shared__ float t[64][65];
  int b = blockIdx.x;
  if (b < 432) {
    wconv_tile(W0, D0, 768, 2304, b / 12, b % 12, t);        // qkv 768x2304
  } else if (b < 576) {
    b -= 432;
    wconv_tile(W1, D1, 768, 768, b / 12, b % 12, t);         // proj 768x768
  } else if (b < 1152) {
    b -= 576;
    wconv_tile(W2, D2, 768, 3072, b / 12, b % 12, t);        // mlp1 768x3072
  } else {
    b -= 1152;
    wconv_tile(W3, D3, 3072, 768, b / 48, b % 48, t);        // mlp2 3072x768
  }
}

// ---------------------------------------------------------------------------
// bf16 MFMA GEMM (m97 structure): out[M,Nn] = act(A[M,K] @ Bt[Nn,K]^T + bias)
// ---------------------------------------------------------------------------
__device__ __forceinline__ float gelu_exact(float x) {
  return 0.5f * x * (1.0f + erff(x * 0.70710678118654752f));
}

template <int ACT, int RES, int OUTBF>
__global__ __launch_bounds__(256) void gemm_mfma(const unsigned short* __restrict__ A,
                                                 const unsigned short* __restrict__ Bt,
                                                 const float* __restrict__ bias, int Nbias,
                                                 float* __restrict__ outf,
                                                 unsigned short* __restrict__ outb,
                                                 int Nn, int K) {
  __shared__ __align__(16) unsigned short As[128 * 32];
  __shared__ __align__(16) unsigned short Bs[128 * 32];
  const int tid = threadIdx.x;
  const int lane = tid & 63, w = tid >> 6;
  const int row0 = blockIdx.y * 128, col0 = blockIdx.x * 128;
  const int wm = (w >> 1) * 64, wn = (w & 1) * 64;
  const int fm = lane & 15, fq = lane >> 4;

  const int c0 = w * 64 + lane;
  const int c1 = c0 + 256;
  const unsigned short* gA0 = A + (size_t)(row0 + (c0 >> 2)) * K + (c0 & 3) * 8;
  const unsigned short* gA1 = A + (size_t)(row0 + (c1 >> 2)) * K + (c1 & 3) * 8;
  const unsigned short* gB0 = Bt + (size_t)(col0 + (c0 >> 2)) * K + (c0 & 3) * 8;
  const unsigned short* gB1 = Bt + (size_t)(col0 + (c1 >> 2)) * K + (c1 & 3) * 8;
  unsigned short* lA0 = As + (size_t)(w * 64) * 8;
  unsigned short* lA1 = As + (size_t)(w * 64 + 256) * 8;
  unsigned short* lB0 = Bs + (size_t)(w * 64) * 8;
  unsigned short* lB1 = Bs + (size_t)(w * 64 + 256) * 8;

  v4f acc[4][4];
#pragma unroll
  for (int i = 0; i < 4; ++i)
#pragma unroll
    for (int j = 0; j < 4; ++j) acc[i][j] = (v4f){0.f, 0.f, 0.f, 0.f};

  for (int k0 = 0; k0 < K; k0 += 32) {
    async16(gA0 + k0, lA0);
    async16(gA1 + k0, lA1);
    async16(gB0 + k0, lB0);
    async16(gB1 + k0, lB1);
    __syncthreads();
    v8s af[4], bf[4];
#pragma unroll
    for (int i = 0; i < 4; ++i)
      af[i] = *(const v8s*)(As + (size_t)(wm + i * 16 + fm) * 32 + fq * 8);
#pragma unroll
    for (int j = 0; j < 4; ++j)
      bf[j] = *(const v8s*)(Bs + (size_t)(wn + j * 16 + fm) * 32 + fq * 8);
#pragma unroll
    for (int i = 0; i < 4; ++i)
#pragma unroll
      for (int j = 0; j < 4; ++j)
        acc[i][j] = __builtin_amdgcn_mfma_f32_16x16x32_bf16(af[i], bf[j], acc[i][j], 0, 0, 0);
    __syncthreads();
  }

#pragma unroll
  for (int i = 0; i < 4; ++i) {
    int row = row0 + wm + i * 16 + fq * 4;
#pragma unroll
    for (int j = 0; j < 4; ++j) {
      int col = col0 + wn + j * 16 + fm;
      float b = (col < Nbias) ? bias[col] : 0.f;
#pragma unroll
      for (int r = 0; r < 4; ++r) {
        float v = acc[i][j][r] + b;
        if (ACT == 1) v = gelu_exact(v);
        size_t o = (size_t)(row + r) * Nn + col;
        if (RES) {
          outf[o] += v;
        } else if (OUTBF) {
          outb[o] = f2bf(v);
        } else {
          outf[o] = v;
        }
      }
    }
  }
}

// ---------------------------------------------------------------------------
// MFMA windowed attention: one wave per (window, head).
// S = Q.K^T (3x3 tiles of 16x16x32), in-register masked softmax (rden folded),
// P (bf16, aliased over Q) . V -> O (3x4 tiles), scatter bf16 store.
// ---------------------------------------------------------------------------
__global__ __launch_bounds__(64) void attn_kernel(const unsigned short* __restrict__ qkv,
                                                  const int* __restrict__ idx,
                                                  const int* __restrict__ capPtr,
                                                  int total,
                                                  unsigned short* __restrict__ attn_out) {
  __shared__ __align__(16) unsigned short QP[CAP * APITCH];  // Q, then P
  __shared__ __align__(16) unsigned short Ks[CAP * APITCH];
  __shared__ __align__(16) unsigned short Vt[64 * APITCH];   // V transposed [d][j]
  __shared__ int vox_lds[64];
  const int cap = *capPtr;
  if (cap > CAP) return;  // loud failure rather than OOB
  const int nw = total / cap;
  const int tasks = nw * NH;
  const int lane = threadIdx.x;
  const int fm = lane & 15, fq = lane >> 4;
  const v8s z8 = {0, 0, 0, 0, 0, 0, 0, 0};

  for (int task = blockIdx.x; task < tasks; task += gridDim.x) {
    const int w = task / NH, hh = task - w * NH;
    int vox_i = NVOX;
    if (lane < cap) vox_i = idx[w * cap + lane];
    vox_lds[lane] = vox_i;
    __syncthreads();

    // stage Q,K: 48 rows x 8 chunks of 8 bf16; lane covers (row, chunk)
#pragma unroll
    for (int it = 0; it < 6; ++it) {
      int id = it * 64 + lane;  // 0..383
      int j = id >> 3, c = id & 7;
      int vj = vox_lds[j];
      v8s q8 = z8, k8 = z8;
      if (vj < NVOX) {
        const unsigned short* base = qkv + (size_t)vj * (3 * CCH) + hh * DH + c * 8;
        q8 = *(const v8s*)(base);
        k8 = *(const v8s*)(base + CCH);
      }
      *(v8s*)(QP + j * APITCH + c * 8) = q8;
      *(v8s*)(Ks + j * APITCH + c * 8) = k8;
    }
    // stage V transposed: lane = d, column j
#pragma unroll 4
    for (int j = 0; j < CAP; ++j) {
      int vj = vox_lds[j];
      unsigned short vv = 0;
      if (vj < NVOX) vv = qkv[(size_t)vj * (3 * CCH) + 2 * CCH + hh * DH + lane];
      Vt[lane * APITCH + j] = vv;
    }
#pragma unroll
    for (int j = CAP; j < 64; ++j) Vt[lane * APITCH + j] = 0;  // k-padding
    __syncthreads();

    // S = Q . K^T  (rows i, cols j)
    v4f s_acc[3][3];
#pragma unroll
    for (int mi = 0; mi < 3; ++mi)
#pragma unroll
      for (int jt = 0; jt < 3; ++jt) s_acc[mi][jt] = (v4f){0.f, 0.f, 0.f, 0.f};
#pragma unroll
    for (int ks = 0; ks < 2; ++ks) {
      v8s qf[3], kf[3];
#pragma unroll
      for (int mi = 0; mi < 3; ++mi)
        qf[mi] = *(const v8s*)(QP + (mi * 16 + fm) * APITCH + ks * 32 + fq * 8);
#pragma unroll
      for (int jt = 0; jt < 3; ++jt)
        kf[jt] = *(const v8s*)(Ks + (jt * 16 + fm) * APITCH + ks * 32 + fq * 8);
#pragma unroll
      for (int mi = 0; mi < 3; ++mi)
#pragma unroll
        for (int jt = 0; jt < 3; ++jt)
          s_acc[mi][jt] = __builtin_amdgcn_mfma_f32_16x16x32_bf16(qf[mi], kf[jt], s_acc[mi][jt], 0, 0, 0);
    }
    __syncthreads();  // Q fragment reads complete before P overwrites QP

    // masked softmax in C-layout registers; scale 1/8 folded into exp,
    // 1/den folded into P. Scores are O(1) here -> exp without max-subtract.
    bool va0 = (fm < cap) && (vox_lds[fm] < NVOX);
    bool va1 = (16 + fm < cap) && (vox_lds[16 + fm] < NVOX);
    bool va2 = (32 + fm < cap) && (vox_lds[32 + fm] < NVOX);
#pragma unroll
    for (int mi = 0; mi < 3; ++mi) {
#pragma unroll
      for (int r = 0; r < 4; ++r) {
        float e0 = va0 ? __expf(s_acc[mi][0][r] * 0.125f) : 0.f;
        float e1 = va1 ? __expf(s_acc[mi][1][r] * 0.125f) : 0.f;
        float e2 = va2 ? __expf(s_acc[mi][2][r] * 0.125f) : 0.f;
        float den = e0 + e1 + e2;
        den += __shfl_xor(den, 1, 64);
        den += __shfl_xor(den, 2, 64);
        den += __shfl_xor(den, 4, 64);
        den += __shfl_xor(den, 8, 64);
        float rden = (den > 0.f) ? 1.0f / den : 0.f;
        int row = mi * 16 + fq * 4 + r;
        QP[row * APITCH + fm] = f2bf(e0 * rden);
        QP[row * APITCH + 16 + fm] = f2bf(e1 * rden);
        QP[row * APITCH + 32 + fm] = f2bf(e2 * rden);
      }
    }
    if (lane < CAP) {  // zero P cols 48..64 (k padding for PV)
      *(v8s*)(QP + lane * APITCH + 48) = z8;
      *(v8s*)(QP + lane * APITCH + 56) = z8;
    }
    __syncthreads();

    // O = P . V   (rows i, cols d)
    v4f o_acc[3][4];
#pragma unroll
    for (int mi = 0; mi < 3; ++mi)
#pragma unroll
      for (int nt = 0; nt < 4; ++nt) o_acc[mi][nt] = (v4f){0.f, 0.f, 0.f, 0.f};
#pragma unroll
    for (int ks = 0; ks < 2; ++ks) {
      v8s pf[3], vf[4];
#pragma unroll
      for (int mi = 0; mi < 3; ++mi)
        pf[mi] = *(const v8s*)(QP + (mi * 16 + fm) * APITCH + ks * 32 + fq * 8);
#pragma unroll
      for (int nt = 0; nt < 4; ++nt)
        vf[nt] = *(const v8s*)(Vt + (nt * 16 + fm) * APITCH + ks * 32 + fq * 8);
#pragma unroll
      for (int mi = 0; mi < 3; ++mi)
#pragma unroll
        for (int nt = 0; nt < 4; ++nt)
          o_acc[mi][nt] = __builtin_amdgcn_mfma_f32_16x16x32_bf16(pf[mi], vf[nt], o_acc[mi][nt], 0, 0, 0);
    }

    // scatter store O rows
#pragma unroll
    for (int mi = 0; mi < 3; ++mi) {
#pragma unroll
      for (int r = 0; r < 4; ++r) {
        int i = mi * 16 + fq * 4 + r;
        int vox = vox_lds[i];
        if (i < cap && vox < NVOX) {
          unsigned short* ob = attn_out + (size_t)vox * CCH + hh * DH + fm;
#pragma unroll
          for (int nt = 0; nt < 4; ++nt) ob[nt * 16] = f2bf(o_acc[mi][nt][r]);
        }
      }
    }
    __syncthreads();  // P/Vt reads done before next task's staging
  }
}

// ---------------------------------------------------------------------------
// gaussian decode: reads padded [N][512] fp32, writes d_out [N][448]
// ---------------------------------------------------------------------------
__global__ __launch_bounds__(256) void decode_kernel(const float* __restrict__ outpad,
                                                     const int* __restrict__ coords,
                                                     const float* __restrict__ perturb,
                                                     float* __restrict__ out) {
  __shared__ float row[OUT_CH];
  const int n = blockIdx.x;
  const float* src = outpad + (size_t)n * OUT_PAD;
  for (int e = threadIdx.x; e < OUT_CH; e += 256) row[e] = src[e];
  __syncthreads();
  float* o = out + (size_t)n * OUT_CH;
  for (int e = threadIdx.x; e < OUT_CH; e += 256) {
    int g = e / 14, j = e - g * 14;
    float v;
    if (j < 3) {
      float xyz = ((float)coords[n * 3 + j] + 0.5f) * (1.0f / 64.0f);
      v = xyz + tanhf(row[g * 3 + j] + perturb[g * 3 + j]) * (0.75f / 64.0f);
    } else if (j < 6) {
      v = row[96 + g * 3 + (j - 3)];
    } else if (j < 9) {
      v = row[192 + g * 3 + (j - 6)];
    } else if (j < 13) {
      v = row[288 + g * 4 + (j - 9)] * 0.1f;
    } else {
      v = row[416 + g];
    }
    o[e] = v;
  }
}

// ---------------------------------------------------------------------------
extern "C" void kernel_launch(void* const* d_in, const int* in_sizes, int n_in,
                              void* d_out, int out_size, void* d_ws, size_t ws_size,
                              hipStream_t stream) {
  const float* feats = (const float*)d_in[0];
  const int* coords = (const int*)d_in[1];
  const float* in_w = (const float*)d_in[2];
  const float* in_b = (const float*)d_in[3];
  const float* qkv_w = (const float*)d_in[4];
  const float* qkv_b = (const float*)d_in[5];
  const float* proj_w = (const float*)d_in[6];
  const float* proj_b = (const float*)d_in[7];
  const float* mlp_w1 = (const float*)d_in[8];
  const float* mlp_b1 = (const float*)d_in[9];
  const float* mlp_w2 = (const float*)d_in[10];
  const float* mlp_b2 = (const float*)d_in[11];
  const float* out_w = (const float*)d_in[12];
  const float* out_b = (const float*)d_in[13];
  const float* perturb = (const float*)d_in[14];
  const int* idx0 = (const int*)d_in[15];
  const int* vslot0 = (const int*)d_in[18];
  const int* idx1 = (const int*)d_in[19];
  const int* vslot1 = (const int*)d_in[22];
  const int total0 = in_sizes[15];
  const int total1 = in_sizes[19];

  char* p = (char*)d_ws;
  int* caps = (int*)p;                                                    // 256 B
  float* h = (float*)(p + 256);                                           // 25165824
  unsigned short* abuf = (unsigned short*)(p + 256 + 25165824);           // 12582912
  unsigned short* big = (unsigned short*)(p + 256 + 37748736);            // 50331648
  unsigned short* wst = (unsigned short*)(p + 256 + 88080384);            // 14155776
  float* outpad = (float*)(p + 256 + 102236160);                          // 16777216
  const size_t OQ = 0;
  const size_t OP = (size_t)768 * 2304;
  const size_t OM1 = OP + (size_t)768 * 768;
  const size_t OM2 = OM1 + (size_t)768 * 3072;

  cap_kernel<<<1, 256, 0, stream>>>(vslot0, vslot1, NVOX, caps);
  embed_kernel<<<(NVOX * CCH + 255) / 256, 256, 0, stream>>>(feats, coords, in_w, in_b, h);

  for (int i = 0; i < NBLK; ++i) {
    const int* idx = (i & 1) ? idx1 : idx0;
    const int* capP = (i & 1) ? caps + 1 : caps;
    const int total = (i & 1) ? total1 : total0;

    wconvert4<<<1728, 256, 0, stream>>>(
        qkv_w + (size_t)i * 768 * 2304, proj_w + (size_t)i * 768 * 768,
        mlp_w1 + (size_t)i * 768 * 3072, mlp_w2 + (size_t)i * 3072 * 768,
        wst + OQ, wst + OP, wst + OM1, wst + OM2);

    ln_kernel<<<NVOX, 256, 0, stream>>>(h, abuf, 1e-6f);
    gemm_mfma<0, 0, 1><<<dim3(18, 64), 256, 0, stream>>>(
        abuf, wst + OQ, qkv_b + (size_t)i * 2304, 2304, nullptr, big, 2304, 768);
    attn_kernel<<<4096, 64, 0, stream>>>(big, idx, capP, total, abuf);
    gemm_mfma<0, 1, 0><<<dim3(6, 64), 256, 0, stream>>>(
        abuf, wst + OP, proj_b + (size_t)i * 768, 768, h, nullptr, 768, 768);
    ln_kernel<<<NVOX, 256, 0, stream>>>(h, abuf, 1e-6f);
    gemm_mfma<1, 0, 1><<<dim3(24, 64), 256, 0, stream>>>(
        abuf, wst + OM1, mlp_b1 + (size_t)i * 3072, 3072, nullptr, big, 3072, 768);
    gemm_mfma<0, 1, 0><<<dim3(6, 64), 256, 0, stream>>>(
        big, wst + OM2, mlp_b2 + (size_t)i * 768, 768, h, nullptr, 768, 3072);
  }

  ln_kernel<<<NVOX, 256, 0, stream>>>(h, abuf, 1e-5f);
  wconvert<<<dim3(8, 12), 256, 0, stream>>>(out_w, wst + OQ, 768, OUT_CH);
  gemm_mfma<0, 0, 0><<<dim3(4, 64), 256, 0, stream>>>(
      abuf, wst + OQ, out_b, OUT_CH, outpad, nullptr, OUT_PAD, 768);
  decode_kernel<<<NVOX, 256, 0, stream>>>(outpad, coords, perturb, (float*)d_out);
}